// Round 1
// baseline (11085.107 us; speedup 1.0000x reference)
//
#include <hip/hip_runtime.h>
#include <hip/hip_bf16.h>
#include <stdint.h>

#define N_NODES 100000
#define N_EDGES 1600000
#define D 512
#define MPAD 100096  // 782 * 128

typedef short short8 __attribute__((ext_vector_type(8)));
typedef float f32x4 __attribute__((ext_vector_type(4)));

__device__ __forceinline__ unsigned short f2bf(float f) {
  unsigned int b = __builtin_bit_cast(unsigned int, f);
  b += 0x7FFFu + ((b >> 16) & 1u);   // round-to-nearest-even
  return (unsigned short)(b >> 16);
}
__device__ __forceinline__ float bf2f(unsigned short u) {
  unsigned int b = ((unsigned int)u) << 16;
  return __builtin_bit_cast(float, b);
}

__global__ void zero_kernel(float4* __restrict__ out, int n4) {
  int i = blockIdx.x * blockDim.x + threadIdx.x;
  if (i < n4) out[i] = make_float4(0.f, 0.f, 0.f, 0.f);
}

// wT[n*D + k] = bf16(w[k*D + n])  (B^T layout for MFMA B-operand [n][k])
__global__ void prep_wT(const float* __restrict__ w, unsigned short* __restrict__ wT) {
  int idx = blockIdx.x * blockDim.x + threadIdx.x;  // 0..262143
  int n = idx & 511;
  int k = idx >> 9;
  wT[(size_t)n * D + k] = f2bf(w[(size_t)k * D + n]);
}

// hp[m][n] = sum_k h[m][k] * w[k][n], output bf16, M padded to MPAD
__launch_bounds__(256)
__global__ void gemm_kernel(const float* __restrict__ h,
                            const unsigned short* __restrict__ wT,
                            unsigned short* __restrict__ hp) {
  __shared__ __align__(16) unsigned short As[128][40];  // +8 pad breaks bank aliasing
  __shared__ __align__(16) unsigned short Bs[128][40];

  const int tid = threadIdx.x;
  const int lane = tid & 63;
  const int wv = tid >> 6;
  const int waveM = wv & 1;
  const int waveN = wv >> 1;
  const int mBase = blockIdx.y * 128;
  const int nBase = blockIdx.x * 128;
  const int quad = lane >> 4;
  const int l16 = lane & 15;

  f32x4 acc[4][4] = {};

  // A staging geometry: 128x32 fp32, 4 passes of (32 rows x 8 thr x float4)
  const int ar = tid >> 3;
  const int ac = (tid & 7) << 2;
  // B staging geometry: 128x32 bf16, 2 passes of (64 rows x 4 thr x ushort8)
  const int br = tid >> 2;
  const int bc = (tid & 3) << 3;

  for (int k0 = 0; k0 < D; k0 += 32) {
    __syncthreads();
    // stage A tile (fp32 -> bf16)
#pragma unroll
    for (int p = 0; p < 4; ++p) {
      int row = p * 32 + ar;
      int gm = mBase + row;
      float4 v;
      if (gm < N_NODES) v = *(const float4*)&h[(size_t)gm * D + k0 + ac];
      else              v = make_float4(0.f, 0.f, 0.f, 0.f);
      unsigned short* dp = &As[row][ac];
      dp[0] = f2bf(v.x); dp[1] = f2bf(v.y); dp[2] = f2bf(v.z); dp[3] = f2bf(v.w);
    }
    // stage B tile (already bf16, N x K layout)
#pragma unroll
    for (int p = 0; p < 2; ++p) {
      int row = p * 64 + br;
      int gn = nBase + row;
      *(uint4*)&Bs[row][bc] = *(const uint4*)&wT[(size_t)gn * D + k0 + bc];
    }
    __syncthreads();

    short8 aF[4], bF[4];
#pragma unroll
    for (int t = 0; t < 4; ++t) {
      aF[t] = *(const short8*)&As[waveM * 64 + t * 16 + l16][quad * 8];
      bF[t] = *(const short8*)&Bs[waveN * 64 + t * 16 + l16][quad * 8];
    }
#pragma unroll
    for (int mt = 0; mt < 4; ++mt)
#pragma unroll
      for (int nt = 0; nt < 4; ++nt)
        acc[mt][nt] = __builtin_amdgcn_mfma_f32_16x16x32_bf16(aF[mt], bF[nt], acc[mt][nt], 0, 0, 0);
  }

  // epilogue: C/D layout col = lane&15, row = quad*4 + r
#pragma unroll
  for (int mt = 0; mt < 4; ++mt) {
#pragma unroll
    for (int nt = 0; nt < 4; ++nt) {
      int col = nBase + waveN * 64 + nt * 16 + l16;
#pragma unroll
      for (int r = 0; r < 4; ++r) {
        int row = mBase + waveM * 64 + mt * 16 + quad * 4 + r;
        hp[(size_t)row * D + col] = f2bf(acc[mt][nt][r]);
      }
    }
  }
}

// one wave per edge: out[dst] += hp[src] * ew  (fp32 atomics)
__global__ void scatter_kernel(const unsigned short* __restrict__ hp,
                               const float* __restrict__ ew,
                               const int* __restrict__ src,
                               const int* __restrict__ dst,
                               float* __restrict__ out) {
  int edge = blockIdx.x * 4 + (threadIdx.x >> 6);
  if (edge >= N_EDGES) return;
  int lane = threadIdx.x & 63;
  int s = src[edge];
  int d = dst[edge];
  float w = ew[edge];
  const unsigned short* row = hp + (size_t)s * D;
  float* orow = out + (size_t)d * D;
#pragma unroll
  for (int it = 0; it < 2; ++it) {
    int base = it * 256 + lane * 4;
    ushort4 v = *(const ushort4*)&row[base];
    atomicAdd(&orow[base + 0], bf2f(v.x) * w);
    atomicAdd(&orow[base + 1], bf2f(v.y) * w);
    atomicAdd(&orow[base + 2], bf2f(v.z) * w);
    atomicAdd(&orow[base + 3], bf2f(v.w) * w);
  }
}

__global__ void relu_kernel(float4* __restrict__ out, int n4) {
  int i = blockIdx.x * blockDim.x + threadIdx.x;
  if (i < n4) {
    float4 v = out[i];
    v.x = fmaxf(v.x, 0.f);
    v.y = fmaxf(v.y, 0.f);
    v.z = fmaxf(v.z, 0.f);
    v.w = fmaxf(v.w, 0.f);
    out[i] = v;
  }
}

extern "C" void kernel_launch(void* const* d_in, const int* in_sizes, int n_in,
                              void* d_out, int out_size, void* d_ws, size_t ws_size,
                              hipStream_t stream) {
  const float* h   = (const float*)d_in[0];
  const float* w   = (const float*)d_in[1];
  const float* ew  = (const float*)d_in[2];
  const int*   src = (const int*)d_in[3];
  const int*   dst = (const int*)d_in[4];
  float* out = (float*)d_out;

  // ws layout: [0, 512KB) wT bf16 ; [512KB, +102.5MB) hp bf16 (MPAD x D)
  unsigned short* wT = (unsigned short*)d_ws;
  unsigned short* hp = (unsigned short*)((char*)d_ws + (size_t)D * D * 2);

  int n4 = out_size / 4;  // 12.8M float4
  zero_kernel<<<(n4 + 255) / 256, 256, 0, stream>>>((float4*)out, n4);
  prep_wT<<<(D * D) / 256, 256, 0, stream>>>(w, wT);
  dim3 ggrid(D / 128, MPAD / 128);  // (4, 782)
  gemm_kernel<<<ggrid, 256, 0, stream>>>(h, wT, hp);
  scatter_kernel<<<N_EDGES / 4, 256, 0, stream>>>(hp, ew, src, dst, out);
  relu_kernel<<<(n4 + 255) / 256, 256, 0, stream>>>((float4*)out, n4);
}

// Round 2
// 1321.219 us; speedup vs baseline: 8.3901x; 8.3901x over previous
//
#include <hip/hip_runtime.h>
#include <hip/hip_bf16.h>
#include <stdint.h>

#define N_NODES 100000
#define N_EDGES 1600000
#define D 512
#define MPAD 100096  // 782 * 128

typedef short short8 __attribute__((ext_vector_type(8)));
typedef float f32x4 __attribute__((ext_vector_type(4)));

__device__ __forceinline__ unsigned short f2bf(float f) {
  unsigned int b = __builtin_bit_cast(unsigned int, f);
  b += 0x7FFFu + ((b >> 16) & 1u);   // round-to-nearest-even
  return (unsigned short)(b >> 16);
}
__device__ __forceinline__ float bf2f(unsigned short u) {
  unsigned int b = ((unsigned int)u) << 16;
  return __builtin_bit_cast(float, b);
}

__global__ void zero_int_kernel(int* __restrict__ p, int n) {
  int i = blockIdx.x * blockDim.x + threadIdx.x;
  if (i < n) p[i] = 0;
}

// wT[n*D + k] = bf16(w[k*D + n])  (B^T layout for MFMA B-operand [n][k])
__global__ void prep_wT(const float* __restrict__ w, unsigned short* __restrict__ wT) {
  int idx = blockIdx.x * blockDim.x + threadIdx.x;  // 0..262143
  int n = idx & 511;
  int k = idx >> 9;
  wT[(size_t)n * D + k] = f2bf(w[(size_t)k * D + n]);
}

// hp[m][n] = sum_k h[m][k] * w[k][n], output bf16, M padded to MPAD
__launch_bounds__(256)
__global__ void gemm_kernel(const float* __restrict__ h,
                            const unsigned short* __restrict__ wT,
                            unsigned short* __restrict__ hp) {
  __shared__ __align__(16) unsigned short As[128][40];
  __shared__ __align__(16) unsigned short Bs[128][40];

  const int tid = threadIdx.x;
  const int lane = tid & 63;
  const int wv = tid >> 6;
  const int waveM = wv & 1;
  const int waveN = wv >> 1;
  const int mBase = blockIdx.y * 128;
  const int nBase = blockIdx.x * 128;
  const int quad = lane >> 4;
  const int l16 = lane & 15;

  f32x4 acc[4][4] = {};

  const int ar = tid >> 3;
  const int ac = (tid & 7) << 2;
  const int br = tid >> 2;
  const int bc = (tid & 3) << 3;

  for (int k0 = 0; k0 < D; k0 += 32) {
    __syncthreads();
#pragma unroll
    for (int p = 0; p < 4; ++p) {
      int row = p * 32 + ar;
      int gm = mBase + row;
      float4 v;
      if (gm < N_NODES) v = *(const float4*)&h[(size_t)gm * D + k0 + ac];
      else              v = make_float4(0.f, 0.f, 0.f, 0.f);
      unsigned short* dp = &As[row][ac];
      dp[0] = f2bf(v.x); dp[1] = f2bf(v.y); dp[2] = f2bf(v.z); dp[3] = f2bf(v.w);
    }
#pragma unroll
    for (int p = 0; p < 2; ++p) {
      int row = p * 64 + br;
      int gn = nBase + row;
      *(uint4*)&Bs[row][bc] = *(const uint4*)&wT[(size_t)gn * D + k0 + bc];
    }
    __syncthreads();

    short8 aF[4], bF[4];
#pragma unroll
    for (int t = 0; t < 4; ++t) {
      aF[t] = *(const short8*)&As[waveM * 64 + t * 16 + l16][quad * 8];
      bF[t] = *(const short8*)&Bs[waveN * 64 + t * 16 + l16][quad * 8];
    }
#pragma unroll
    for (int mt = 0; mt < 4; ++mt)
#pragma unroll
      for (int nt = 0; nt < 4; ++nt)
        acc[mt][nt] = __builtin_amdgcn_mfma_f32_16x16x32_bf16(aF[mt], bF[nt], acc[mt][nt], 0, 0, 0);
  }

#pragma unroll
  for (int mt = 0; mt < 4; ++mt) {
#pragma unroll
    for (int nt = 0; nt < 4; ++nt) {
      int col = nBase + waveN * 64 + nt * 16 + l16;
#pragma unroll
      for (int r = 0; r < 4; ++r) {
        int row = mBase + waveM * 64 + mt * 16 + quad * 4 + r;
        hp[(size_t)row * D + col] = f2bf(acc[mt][nt][r]);
      }
    }
  }
}

// deg[dst[e]]++ over all edges
__global__ void hist_kernel(const int* __restrict__ dst, int* __restrict__ deg) {
  int e = blockIdx.x * blockDim.x + threadIdx.x;
  if (e < N_EDGES) atomicAdd(&deg[dst[e]], 1);
}

// single-block exclusive scan of deg -> offs (and cursor copy)
#define SCAN_T 1024
#define CHUNK 98  // 1024*98 = 100352 >= 100000
__launch_bounds__(1024)
__global__ void scan_kernel(const int* __restrict__ deg,
                            int* __restrict__ offs, int* __restrict__ cursor) {
  __shared__ int sums[SCAN_T];
  int t = threadIdx.x;
  int base = t * CHUNK;
  int local = 0;
  for (int i = 0; i < CHUNK; ++i) {
    int idx = base + i;
    if (idx < N_NODES) local += deg[idx];
  }
  sums[t] = local;
  __syncthreads();
  // Hillis-Steele inclusive scan over 1024 partials
  for (int off = 1; off < SCAN_T; off <<= 1) {
    int v = (t >= off) ? sums[t - off] : 0;
    __syncthreads();
    sums[t] += v;
    __syncthreads();
  }
  int run = (t == 0) ? 0 : sums[t - 1];  // exclusive prefix of this chunk
  for (int i = 0; i < CHUNK; ++i) {
    int idx = base + i;
    if (idx < N_NODES) {
      offs[idx] = run;
      cursor[idx] = run;
      run += deg[idx];
    }
  }
}

// counting-sort edges by dst: csr[pos] = (src, bitcast(ew))
__global__ void build_csr_kernel(const int* __restrict__ src, const int* __restrict__ dst,
                                 const float* __restrict__ ew,
                                 int* __restrict__ cursor, int2* __restrict__ csr) {
  int e = blockIdx.x * blockDim.x + threadIdx.x;
  if (e < N_EDGES) {
    int d = dst[e];
    int pos = atomicAdd(&cursor[d], 1);
    int2 rec;
    rec.x = src[e];
    rec.y = __builtin_bit_cast(int, ew[e]);
    csr[pos] = rec;
  }
}

// one block per dst node: out[node] = relu(sum_e ew * hp[src_e]); fused zero+relu
__launch_bounds__(256)
__global__ void gather_kernel(const unsigned short* __restrict__ hp,
                              const int2* __restrict__ csr,
                              const int* __restrict__ offs,
                              const int* __restrict__ deg,
                              float* __restrict__ out) {
  int node = blockIdx.x;
  int tid = threadIdx.x;
  int start = offs[node];
  int cnt = deg[node];
  const int2* ep = csr + start;
  float a0 = 0.f, a1 = 0.f;
  int col = tid * 2;
  for (int j = 0; j < cnt; ++j) {
    int2 e = ep[j];
    float wgt = __builtin_bit_cast(float, e.y);
    unsigned int v = *(const unsigned int*)&hp[(size_t)e.x * D + col];
    a0 += bf2f((unsigned short)(v & 0xffffu)) * wgt;
    a1 += bf2f((unsigned short)(v >> 16)) * wgt;
  }
  float2 r;
  r.x = fmaxf(a0, 0.f);
  r.y = fmaxf(a1, 0.f);
  *(float2*)&out[(size_t)node * D + col] = r;
}

extern "C" void kernel_launch(void* const* d_in, const int* in_sizes, int n_in,
                              void* d_out, int out_size, void* d_ws, size_t ws_size,
                              hipStream_t stream) {
  const float* h   = (const float*)d_in[0];
  const float* w   = (const float*)d_in[1];
  const float* ew  = (const float*)d_in[2];
  const int*   src = (const int*)d_in[3];
  const int*   dst = (const int*)d_in[4];
  float* out = (float*)d_out;

  // ws layout (16B aligned):
  char* p = (char*)d_ws;
  unsigned short* wT = (unsigned short*)p;            p += (size_t)D * D * 2;            // 512 KB
  unsigned short* hp = (unsigned short*)p;            p += (size_t)MPAD * D * 2;         // 102.5 MB
  int* deg    = (int*)p;                              p += (size_t)N_NODES * 4;          // 400 KB
  int* offs   = (int*)p;                              p += (size_t)N_NODES * 4;
  int* cursor = (int*)p;                              p += (size_t)N_NODES * 4;
  int2* csr   = (int2*)p;                             // 12.8 MB

  zero_int_kernel<<<(N_NODES + 255) / 256, 256, 0, stream>>>(deg, N_NODES);
  prep_wT<<<(D * D) / 256, 256, 0, stream>>>(w, wT);
  gemm_kernel<<<dim3(D / 128, MPAD / 128), 256, 0, stream>>>(h, wT, hp);
  hist_kernel<<<(N_EDGES + 255) / 256, 256, 0, stream>>>(dst, deg);
  scan_kernel<<<1, SCAN_T, 0, stream>>>(deg, offs, cursor);
  build_csr_kernel<<<(N_EDGES + 255) / 256, 256, 0, stream>>>(src, dst, ew, cursor, csr);
  gather_kernel<<<N_NODES, 256, 0, stream>>>(hp, csr, offs, deg, out);
}

// Round 3
// 869.870 us; speedup vs baseline: 12.7434x; 1.5189x over previous
//
#include <hip/hip_runtime.h>
#include <hip/hip_bf16.h>
#include <stdint.h>

#define N_NODES 100000
#define N_EDGES 1600000
#define D 512
#define MPAD 100096  // 782 * 128

typedef short short8 __attribute__((ext_vector_type(8)));
typedef float f32x4 __attribute__((ext_vector_type(4)));

typedef __attribute__((address_space(3))) void lds_void;
typedef __attribute__((address_space(1))) void glob_void;

__device__ __forceinline__ void async_ld16(const void* g, void* l) {
  __builtin_amdgcn_global_load_lds((glob_void*)g, (lds_void*)l, 16, 0, 0);
}

__device__ __forceinline__ unsigned short f2bf(float f) {
  unsigned int b = __builtin_bit_cast(unsigned int, f);
  b += 0x7FFFu + ((b >> 16) & 1u);   // round-to-nearest-even
  return (unsigned short)(b >> 16);
}
__device__ __forceinline__ float bf2f(unsigned short u) {
  unsigned int b = ((unsigned int)u) << 16;
  return __builtin_bit_cast(float, b);
}

__global__ void zero_int_kernel(int* __restrict__ p, int n) {
  int i = blockIdx.x * blockDim.x + threadIdx.x;
  if (i < n) p[i] = 0;
}

// wT[n*D + k] = bf16(w[k*D + n])  (B^T layout for MFMA B-operand [n][k])
__global__ void prep_wT(const float* __restrict__ w, unsigned short* __restrict__ wT) {
  int idx = blockIdx.x * blockDim.x + threadIdx.x;
  int n = idx & 511;
  int k = idx >> 9;
  wT[(size_t)n * D + k] = f2bf(w[(size_t)k * D + n]);
}

// h (fp32) -> hb (bf16), 4 elems/thread
__global__ void convert_h(const float4* __restrict__ h4, ushort4* __restrict__ hb4, int n4) {
  int i = blockIdx.x * blockDim.x + threadIdx.x;
  if (i < n4) {
    float4 v = h4[i];
    ushort4 o;
    o.x = f2bf(v.x); o.y = f2bf(v.y); o.z = f2bf(v.z); o.w = f2bf(v.w);
    hb4[i] = o;
  }
}

// ---- fast path GEMM: bf16 A via global_load_lds, XOR-swizzled LDS ----
// LDS tile: 128 rows x 64 cols bf16, row-major, 16B block b of row r holds
// global col-block (b ^ (r&7)). Staged contiguously in lane order (required
// by global_load_lds wave-uniform-base semantics).
__launch_bounds__(256)
__global__ void gemm_lds_kernel(const unsigned short* __restrict__ hb,
                                const unsigned short* __restrict__ wT,
                                unsigned short* __restrict__ hp) {
  __shared__ __align__(16) unsigned short As[128 * 64];  // 16 KB
  __shared__ __align__(16) unsigned short Bs[128 * 64];  // 16 KB

  const int tid = threadIdx.x;
  const int lane = tid & 63;
  const int wv = tid >> 6;
  const int waveM = wv & 1;
  const int waveN = wv >> 1;
  const int mBase = blockIdx.y * 128;
  const int nBase = blockIdx.x * 128;
  const int quad = lane >> 4;
  const int l16 = lane & 15;

  f32x4 acc[4][4] = {};

  const unsigned short* aBase = hb + (size_t)mBase * D;
  const unsigned short* bBase = wT + (size_t)nBase * D;

  for (int k0 = 0; k0 < D; k0 += 64) {
    __syncthreads();
#pragma unroll
    for (int p = 0; p < 4; ++p) {
      int idx = p * 256 + tid;
      int r = idx >> 3;
      int b = idx & 7;
      int sb = b ^ (r & 7);                     // source col-block (swizzle)
      unsigned short* la = &As[(size_t)(p * 256 + wv * 64) * 8];  // wave-uniform
      unsigned short* lb = &Bs[(size_t)(p * 256 + wv * 64) * 8];
      async_ld16(aBase + (size_t)r * D + k0 + sb * 8, la);
      async_ld16(bBase + (size_t)r * D + k0 + sb * 8, lb);
    }
    __syncthreads();

#pragma unroll
    for (int kk = 0; kk < 2; ++kk) {
      short8 aF[4], bF[4];
#pragma unroll
      for (int t = 0; t < 4; ++t) {
        int rA = waveM * 64 + t * 16 + l16;
        int rB = waveN * 64 + t * 16 + l16;
        int blk = (kk * 4 + quad) ^ (l16 & 7);  // read-side swizzle
        aF[t] = *(const short8*)&As[rA * 64 + blk * 8];
        bF[t] = *(const short8*)&Bs[rB * 64 + blk * 8];
      }
#pragma unroll
      for (int mt = 0; mt < 4; ++mt)
#pragma unroll
        for (int nt = 0; nt < 4; ++nt)
          acc[mt][nt] = __builtin_amdgcn_mfma_f32_16x16x32_bf16(aF[mt], bF[nt], acc[mt][nt], 0, 0, 0);
    }
  }

#pragma unroll
  for (int mt = 0; mt < 4; ++mt) {
#pragma unroll
    for (int nt = 0; nt < 4; ++nt) {
      int col = nBase + waveN * 64 + nt * 16 + l16;
#pragma unroll
      for (int r = 0; r < 4; ++r) {
        int row = mBase + waveM * 64 + mt * 16 + quad * 4 + r;
        hp[(size_t)row * D + col] = f2bf(acc[mt][nt][r]);
      }
    }
  }
}

// ---- fallback GEMM (round-2): fp32 A staging, used if ws too small ----
__launch_bounds__(256)
__global__ void gemm_fp32a_kernel(const float* __restrict__ h,
                                  const unsigned short* __restrict__ wT,
                                  unsigned short* __restrict__ hp) {
  __shared__ __align__(16) unsigned short As[128][40];
  __shared__ __align__(16) unsigned short Bs[128][40];

  const int tid = threadIdx.x;
  const int lane = tid & 63;
  const int wv = tid >> 6;
  const int waveM = wv & 1;
  const int waveN = wv >> 1;
  const int mBase = blockIdx.y * 128;
  const int nBase = blockIdx.x * 128;
  const int quad = lane >> 4;
  const int l16 = lane & 15;

  f32x4 acc[4][4] = {};
  const int ar = tid >> 3;
  const int ac = (tid & 7) << 2;
  const int br = tid >> 2;
  const int bc = (tid & 3) << 3;

  for (int k0 = 0; k0 < D; k0 += 32) {
    __syncthreads();
#pragma unroll
    for (int p = 0; p < 4; ++p) {
      int row = p * 32 + ar;
      int gm = mBase + row;
      float4 v;
      if (gm < N_NODES) v = *(const float4*)&h[(size_t)gm * D + k0 + ac];
      else              v = make_float4(0.f, 0.f, 0.f, 0.f);
      unsigned short* dp = &As[row][ac];
      dp[0] = f2bf(v.x); dp[1] = f2bf(v.y); dp[2] = f2bf(v.z); dp[3] = f2bf(v.w);
    }
#pragma unroll
    for (int p = 0; p < 2; ++p) {
      int row = p * 64 + br;
      *(uint4*)&Bs[row][bc] = *(const uint4*)&wT[(size_t)(nBase + row) * D + k0 + bc];
    }
    __syncthreads();

    short8 aF[4], bF[4];
#pragma unroll
    for (int t = 0; t < 4; ++t) {
      aF[t] = *(const short8*)&As[waveM * 64 + t * 16 + l16][quad * 8];
      bF[t] = *(const short8*)&Bs[waveN * 64 + t * 16 + l16][quad * 8];
    }
#pragma unroll
    for (int mt = 0; mt < 4; ++mt)
#pragma unroll
      for (int nt = 0; nt < 4; ++nt)
        acc[mt][nt] = __builtin_amdgcn_mfma_f32_16x16x32_bf16(aF[mt], bF[nt], acc[mt][nt], 0, 0, 0);
  }

#pragma unroll
  for (int mt = 0; mt < 4; ++mt) {
#pragma unroll
    for (int nt = 0; nt < 4; ++nt) {
      int col = nBase + waveN * 64 + nt * 16 + l16;
#pragma unroll
      for (int r = 0; r < 4; ++r) {
        int row = mBase + waveM * 64 + mt * 16 + quad * 4 + r;
        hp[(size_t)row * D + col] = f2bf(acc[mt][nt][r]);
      }
    }
  }
}

// deg[dst[e]]++ over all edges, 4 edges/thread
__global__ void hist_kernel(const int4* __restrict__ dst4, int* __restrict__ deg) {
  int i = blockIdx.x * blockDim.x + threadIdx.x;
  if (i < N_EDGES / 4) {
    int4 d = dst4[i];
    atomicAdd(&deg[d.x], 1);
    atomicAdd(&deg[d.y], 1);
    atomicAdd(&deg[d.z], 1);
    atomicAdd(&deg[d.w], 1);
  }
}

// single-block exclusive scan, vectorized: 1024 threads x 100 elems
__launch_bounds__(1024)
__global__ void scan_kernel(const int* __restrict__ deg,
                            int* __restrict__ offs, int* __restrict__ cursor) {
  __shared__ int sums[1024];
  int t = threadIdx.x;
  int base = t * 100;
  int local = 0;
  if (base < N_NODES) {
    const int4* d4 = (const int4*)(deg + base);
#pragma unroll
    for (int i = 0; i < 25; ++i) {
      int4 v = d4[i];
      local += v.x + v.y + v.z + v.w;
    }
  }
  sums[t] = local;
  __syncthreads();
  for (int off = 1; off < 1024; off <<= 1) {
    int v = (t >= off) ? sums[t - off] : 0;
    __syncthreads();
    sums[t] += v;
    __syncthreads();
  }
  if (base < N_NODES) {
    int run = (t == 0) ? 0 : sums[t - 1];
    const int4* d4 = (const int4*)(deg + base);
    int4* o4 = (int4*)(offs + base);
    int4* c4 = (int4*)(cursor + base);
#pragma unroll
    for (int i = 0; i < 25; ++i) {
      int4 v = d4[i];
      int4 o;
      o.x = run;
      o.y = o.x + v.x;
      o.z = o.y + v.y;
      o.w = o.z + v.z;
      run = o.w + v.w;
      o4[i] = o;
      c4[i] = o;
    }
  }
}

// counting-sort edges by dst: csr[pos] = (src, bitcast(ew))
__global__ void build_csr_kernel(const int* __restrict__ src, const int* __restrict__ dst,
                                 const float* __restrict__ ew,
                                 int* __restrict__ cursor, int2* __restrict__ csr) {
  int e = blockIdx.x * blockDim.x + threadIdx.x;
  if (e < N_EDGES) {
    int d = dst[e];
    int pos = atomicAdd(&cursor[d], 1);
    int2 rec;
    rec.x = src[e];
    rec.y = __builtin_bit_cast(int, ew[e]);
    csr[pos] = rec;
  }
}

// one (node, col-half) per 64-thread block; 2 col-passes for L3 residency.
// x-major dispatch => pass 0 (cols 0-255) mostly completes before pass 1.
__launch_bounds__(64)
__global__ void gather_kernel(const unsigned short* __restrict__ hp,
                              const int2* __restrict__ csr,
                              const int* __restrict__ offs,
                              const int* __restrict__ deg,
                              float* __restrict__ out) {
  int node = blockIdx.x;
  int col = blockIdx.y * 256 + threadIdx.x * 4;
  int start = offs[node];
  int cnt = deg[node];
  const int2* ep = csr + start;
  float a0 = 0.f, a1 = 0.f, a2 = 0.f, a3 = 0.f;
  int j = 0;
  for (; j + 2 <= cnt; j += 2) {
    int2 e0 = ep[j];
    int2 e1 = ep[j + 1];
    ushort4 v0 = *(const ushort4*)&hp[(size_t)e0.x * D + col];
    ushort4 v1 = *(const ushort4*)&hp[(size_t)e1.x * D + col];
    float w0 = __builtin_bit_cast(float, e0.y);
    float w1 = __builtin_bit_cast(float, e1.y);
    a0 += bf2f(v0.x) * w0; a1 += bf2f(v0.y) * w0;
    a2 += bf2f(v0.z) * w0; a3 += bf2f(v0.w) * w0;
    a0 += bf2f(v1.x) * w1; a1 += bf2f(v1.y) * w1;
    a2 += bf2f(v1.z) * w1; a3 += bf2f(v1.w) * w1;
  }
  if (j < cnt) {
    int2 e = ep[j];
    ushort4 v = *(const ushort4*)&hp[(size_t)e.x * D + col];
    float w0 = __builtin_bit_cast(float, e.y);
    a0 += bf2f(v.x) * w0; a1 += bf2f(v.y) * w0;
    a2 += bf2f(v.z) * w0; a3 += bf2f(v.w) * w0;
  }
  float4 r;
  r.x = fmaxf(a0, 0.f);
  r.y = fmaxf(a1, 0.f);
  r.z = fmaxf(a2, 0.f);
  r.w = fmaxf(a3, 0.f);
  *(float4*)&out[(size_t)node * D + col] = r;
}

extern "C" void kernel_launch(void* const* d_in, const int* in_sizes, int n_in,
                              void* d_out, int out_size, void* d_ws, size_t ws_size,
                              hipStream_t stream) {
  const float* h   = (const float*)d_in[0];
  const float* w   = (const float*)d_in[1];
  const float* ew  = (const float*)d_in[2];
  const int*   src = (const int*)d_in[3];
  const int*   dst = (const int*)d_in[4];
  float* out = (float*)d_out;

  // ws layout: wT | hp | deg | offs | cursor | csr | [hb if room]
  char* p = (char*)d_ws;
  unsigned short* wT = (unsigned short*)p;  p += (size_t)D * D * 2;          // 512 KB
  unsigned short* hp = (unsigned short*)p;  p += (size_t)MPAD * D * 2;       // 102.5 MB
  int* deg    = (int*)p;                    p += (size_t)N_NODES * 4;
  int* offs   = (int*)p;                    p += (size_t)N_NODES * 4;
  int* cursor = (int*)p;                    p += (size_t)N_NODES * 4;
  int2* csr   = (int2*)p;                   p += (size_t)N_EDGES * 8;        // 12.8 MB
  unsigned short* hb = (unsigned short*)p;                                   // 102.5 MB (optional)
  size_t need_fast = (size_t)(p - (char*)d_ws) + (size_t)MPAD * D * 2;
  bool fast = ws_size >= need_fast;

  zero_int_kernel<<<(N_NODES + 255) / 256, 256, 0, stream>>>(deg, N_NODES);
  prep_wT<<<(D * D) / 256, 256, 0, stream>>>(w, wT);
  hist_kernel<<<(N_EDGES / 4 + 255) / 256, 256, 0, stream>>>((const int4*)dst, deg);
  scan_kernel<<<1, 1024, 0, stream>>>(deg, offs, cursor);
  build_csr_kernel<<<(N_EDGES + 255) / 256, 256, 0, stream>>>(src, dst, ew, cursor, csr);

  if (fast) {
    int n4 = N_NODES * D / 4;  // 12.8M
    convert_h<<<(n4 + 255) / 256, 256, 0, stream>>>((const float4*)h, (ushort4*)hb, n4);
    gemm_lds_kernel<<<dim3(D / 128, MPAD / 128), 256, 0, stream>>>(hb, wT, hp);
  } else {
    gemm_fp32a_kernel<<<dim3(D / 128, MPAD / 128), 256, 0, stream>>>(h, wT, hp);
  }
  gather_kernel<<<dim3(N_NODES, 2), 64, 0, stream>>>(hp, csr, offs, deg, out);
}